// Round 5
// baseline (333.034 us; speedup 1.0000x reference)
//
#include <hip/hip_runtime.h>
#include <hip/hip_fp16.h>

#define NCH 64
#define EPS 1e-5f
#define SBANKS 32   // stats atomic banks
#define BSHIFT 8    // 256 dst nodes per bucket
#define NHIST 768   // blocks in hist pass (3/CU)
#define BINCAP 1600 // max edges per k_bin block (LDS ~21KB -> 4 blocks/CU @512thr)
#define NBINMIN 1024 // min k_bin blocks (4/CU)
#define PADRES 2048 // per-bucket csr slack for 8-padding (256*7 + align < 2048)
#define RSHIFT 14   // src-range windows of 16384 rows (2MB) for L2 locality
#define SRCMASK 0x1FFFFu
#define QW_SCALE 32767.0f
#define QW_INV (1.0f/32767.0f)

typedef _Float16 f16x8 __attribute__((ext_vector_type(8)));
typedef float f32x4 __attribute__((ext_vector_type(4)));

// ---------------- fused front: x cast + W1/W2 pack + bucket histogram ----------------
__global__ __launch_bounds__(256) void k_front(const float* __restrict__ x, __half* __restrict__ xh,
                                               int castTotal, int castB,
                                               const float* __restrict__ W1, _Float16* __restrict__ Wb1,
                                               const float* __restrict__ W2, _Float16* __restrict__ Wb2,
                                               const int* __restrict__ dst, int* __restrict__ cnt,
                                               int E, int per, int nbuck) {
    int bid = blockIdx.x;
    if (bid < castB) {
        int i = (bid * 256 + threadIdx.x) * 4;
        if (i < castTotal) {
            float4 f = *(const float4*)(x + i);
            __half2* o = (__half2*)(xh + i);
            o[0] = __floats2half2_rn(f.x, f.y);
            o[1] = __floats2half2_rn(f.z, f.w);
        }
        return;
    }
    if (bid < castB + 96) {
        // W pack: Wb[((tile*6+kk)*64+lane)*8+j] = W[kk*32+(lane>>4)*8+j][tile*16+(lane&15)]
        int wb = bid - castB;
        const float* W = (wb < 48) ? W1 : W2;
        _Float16* Wb = (wb < 48) ? Wb1 : Wb2;
        int idx = (wb % 48) * 256 + threadIdx.x;   // 0..12287
        int j = idx & 7;
        int lane = (idx >> 3) & 63;
        int tk = idx >> 9;
        int tile = tk / 6, kk = tk % 6;
        int k = kk * 32 + (lane >> 4) * 8 + j;
        int n = tile * 16 + (lane & 15);
        Wb[idx] = (_Float16)W[k * 64 + n];
        return;
    }
    // histogram role
    __shared__ int lh[512];
    int hb = bid - castB - 96;
    for (int t = threadIdx.x; t < nbuck; t += 256) lh[t] = 0;
    __syncthreads();
    int lo = hb * per, hi = min(E, lo + per);
    for (int e = lo + threadIdx.x; e < hi; e += 256)
        atomicAdd(&lh[dst[e] >> BSHIFT], 1);
    __syncthreads();
    for (int t = threadIdx.x; t < nbuck; t += 256)
        if (lh[t]) atomicAdd(&cnt[t], lh[t]);
}

// ---------------- scan bucket counts -> base & cursor ----------------
__global__ void k_bscan(const int* __restrict__ cnt, int* __restrict__ gbase,
                        int* __restrict__ gcur, int nbuck, int E) {
    __shared__ int s[512];
    int t = threadIdx.x;
    int v = (t < nbuck) ? cnt[t] : 0;
    s[t] = v;
    __syncthreads();
    for (int off = 1; off < 512; off <<= 1) {
        int add = (t >= off) ? s[t - off] : 0;
        __syncthreads();
        s[t] += add;
        __syncthreads();
    }
    if (t < nbuck) { int ex = s[t] - v; gbase[t] = ex; gcur[t] = ex; }
    if (t == 0) gbase[nbuck] = E;
}

// ---------------- bin edges into bucket segments (LDS counting sort) ----------------
// 512 threads/block, 1-entry-per-thread scan; ~21KB LDS -> 4 blocks/CU (R3 PMC
// showed 256-block version at 7% occupancy, 40us: pure latency starvation).
__global__ __launch_bounds__(512) void k_bin(const int* __restrict__ src,
                                             const int* __restrict__ dst,
                                             int* __restrict__ gcur,
                                             int2* __restrict__ binned, int E, int per, int nbuck) {
    __shared__ int lh[512];     // per-block bucket counts
    __shared__ int lsc[512];    // exclusive scan (local run starts)
    __shared__ int lbase[512];  // reserved global run bases
    __shared__ int lcur[512];   // scatter cursors
    __shared__ int2 sedge[BINCAP];
    int t = threadIdx.x;
    lh[t] = 0;
    __syncthreads();
    int lo = blockIdx.x * per, hi = min(E, lo + per);
    for (int e = lo + t; e < hi; e += 512)
        atomicAdd(&lh[dst[e] >> BSHIFT], 1);
    __syncthreads();
    int v = lh[t];
    lsc[t] = v;
    __syncthreads();
    for (int off = 1; off < 512; off <<= 1) {
        int add = (t >= off) ? lsc[t - off] : 0;
        __syncthreads();
        lsc[t] += add;
        __syncthreads();
    }
    lsc[t] -= v;   // own slot only: no race
    if (t < nbuck && v) lbase[t] = atomicAdd(&gcur[t], v);
    lcur[t] = lsc[t];
    __syncthreads();
    for (int e = lo + t; e < hi; e += 512) {
        int d = dst[e];
        int b = d >> BSHIFT;
        int pos = atomicAdd(&lcur[b], 1);
        sedge[pos] = make_int2(src[e], d);
    }
    __syncthreads();
    int cntE = hi - lo;
    for (int i = t; i < cntE; i += 512) {
        int2 sd = sedge[i];
        int b = sd.y >> BSHIFT;
        binned[lbase[b] + (i - lsc[b])] = sd;
    }
}

// ---------------- per-bucket CSR build, rows padded to x8, src-range ordered ----------------
// rowinfo[node] = {csr start (8-aligned), padded deg}. Within each row, edges are
// grouped by src>>RSHIFT (8 ascending 2MB windows) so concurrently-running prop
// waves gather within an L2-resident window. Padding slots: row's first src, qw=0.
// 512 threads/block: grid (391) is <2/CU, so fatter blocks double waves/CU for
// the latency-bound edge loops. Per-node phases guarded to t<256.
__global__ __launch_bounds__(512) void k_bucket(const int2* __restrict__ binned,
                                                const int* __restrict__ gbase,
                                                float* __restrict__ dinv,
                                                int2* __restrict__ rowinfo,
                                                unsigned int* __restrict__ csr, int N, int nbuck) {
    __shared__ int hist8[256 * 8];   // (node, src-range) counts
    __shared__ int cur8[256 * 8];    // scatter cursors
    __shared__ int ldeg[256];
    __shared__ int ltmp[256];
    int b = blockIdx.x;
    int t = threadIdx.x;
    int nodeLo = b << BSHIFT;
    int nHere = min(256, N - nodeLo);
    int e0 = gbase[b], e1 = gbase[b + 1];
    int pb = (gbase[b] + b * PADRES + 7) & ~7;   // 8-aligned padded base
    for (int i = t; i < 256 * 8; i += 512) hist8[i] = 0;
    __syncthreads();
    for (int e = e0 + t; e < e1; e += 512) {
        int2 sd = binned[e];
        atomicAdd(&hist8[((sd.y - nodeLo) << 3) + (sd.x >> RSHIFT)], 1);
    }
    __syncthreads();
    int c[8], deg = 0, pdeg = 0;
    if (t < 256) {
#pragma unroll
        for (int r = 0; r < 8; r++) { c[r] = hist8[(t << 3) + r]; deg += c[r]; }
        pdeg = (deg + 7) & ~7;
        ldeg[t] = deg;
        if (t < nHere) dinv[nodeLo + t] = (deg > 0) ? rsqrtf((float)deg) : 0.0f;
        ltmp[t] = pdeg;
    }
    __syncthreads();
    for (int off = 1; off < 256; off <<= 1) {
        int add = (t >= off && t < 256) ? ltmp[t - off] : 0;
        __syncthreads();
        if (t < 256) ltmp[t] += add;
        __syncthreads();
    }
    if (t < 256) {
        int lstart = ltmp[t] - pdeg;
        if (t < nHere) rowinfo[nodeLo + t] = make_int2(pb + lstart, pdeg);
        // within-row range starts
        int run = lstart;
#pragma unroll
        for (int r = 0; r < 8; r++) { cur8[(t << 3) + r] = run; run += c[r]; }
    }
    __syncthreads();
    for (int e = e0 + t; e < e1; e += 512) {
        int2 sd = binned[e];
        int dl = sd.y - nodeLo;
        int pos = atomicAdd(&cur8[(dl << 3) + (sd.x >> RSHIFT)], 1);
        unsigned int dd = (unsigned int)min(ldeg[dl], 32767);
        csr[pb + pos] = (unsigned int)sd.x | (dd << 17);
    }
    __syncthreads();
    if (t < nHere) {
        int d = ldeg[t];
        int pd = (d + 7) & ~7;
        if (pd > d) {
            int lstart = ltmp[t] - pd;
            unsigned int fill = (d > 0) ? (csr[pb + lstart] & SRCMASK) : 0u;  // qw=0 dummy
            for (int i = d; i < pd; i++) csr[pb + lstart + i] = fill;
        }
    }
}

// ---------------- finalize weights: |w| = dinv[s]*rsqrt(deg_d), 15-bit fixed-point ----------------
__global__ void k_weights(unsigned int* __restrict__ csr, const float* __restrict__ dinv, int PE) {
    int e = blockIdx.x * blockDim.x + threadIdx.x;
    if (e < PE) {
        unsigned int v = csr[e];
        unsigned int d = v >> 17;
        if (d == 0) return;                       // padding dummy: keep qw=0
        unsigned int s = v & SRCMASK;
        float aw = dinv[s] * rsqrtf((float)d);    // in [0,1]
        unsigned int qw = (unsigned int)(aw * QW_SCALE + 0.5f);
        csr[e] = s | (qw << 17);
    }
}

// ---------------- propagation: y = [2*]prop(gnorm(h)) [- tnorm(tx0)] ----------------
// Wave = 8 dst nodes; 8-lane group per node; lane owns 8 fixed channels (16B).
// Rows padded to x8 and src-range-ordered: pure unroll-8 body, no tail.
// (R0 structure: plain loop. Pipeline and degree-sort variants both measured
//  slower: ILP<->TLP trade ~1:1; perm scatter kills write locality.)

#define GATH(A0,A1,A2,A3,A4,A5,A6,A7, C0, C1) \
    A0 = *(const uint4*)(hb + (size_t)(C0.x & SRCMASK) * NCH); \
    A1 = *(const uint4*)(hb + (size_t)(C0.y & SRCMASK) * NCH); \
    A2 = *(const uint4*)(hb + (size_t)(C0.z & SRCMASK) * NCH); \
    A3 = *(const uint4*)(hb + (size_t)(C0.w & SRCMASK) * NCH); \
    A4 = *(const uint4*)(hb + (size_t)(C1.x & SRCMASK) * NCH); \
    A5 = *(const uint4*)(hb + (size_t)(C1.y & SRCMASK) * NCH); \
    A6 = *(const uint4*)(hb + (size_t)(C1.z & SRCMASK) * NCH); \
    A7 = *(const uint4*)(hb + (size_t)(C1.w & SRCMASK) * NCH);

#define FMA1(A, W) { \
    float2 f; \
    f = __half22float2(*(const __half2*)&A.x); acc[0] = fmaf(W, f.x, acc[0]); acc[1] = fmaf(W, f.y, acc[1]); \
    f = __half22float2(*(const __half2*)&A.y); acc[2] = fmaf(W, f.x, acc[2]); acc[3] = fmaf(W, f.y, acc[3]); \
    f = __half22float2(*(const __half2*)&A.z); acc[4] = fmaf(W, f.x, acc[4]); acc[5] = fmaf(W, f.y, acc[5]); \
    f = __half22float2(*(const __half2*)&A.w); acc[6] = fmaf(W, f.x, acc[6]); acc[7] = fmaf(W, f.y, acc[7]); }

#define FMA8(A0,A1,A2,A3,A4,A5,A6,A7, C0, C1) { \
    float w0 = -(float)(C0.x >> 17) * QW_INV; \
    float w1 = -(float)(C0.y >> 17) * QW_INV; \
    float w2 = -(float)(C0.z >> 17) * QW_INV; \
    float w3 = -(float)(C0.w >> 17) * QW_INV; \
    float w4 = -(float)(C1.x >> 17) * QW_INV; \
    float w5 = -(float)(C1.y >> 17) * QW_INV; \
    float w6 = -(float)(C1.z >> 17) * QW_INV; \
    float w7 = -(float)(C1.w >> 17) * QW_INV; \
    sw += ((w0 + w1) + (w2 + w3)) + ((w4 + w5) + (w6 + w7)); \
    FMA1(A0, w0) FMA1(A1, w1) FMA1(A2, w2) FMA1(A3, w3) \
    FMA1(A4, w4) FMA1(A5, w5) FMA1(A6, w6) FMA1(A7, w7) }

__global__ __launch_bounds__(256) void k_prop(const __half* __restrict__ h,
                                              const int2* __restrict__ rowinfo,
                                              const unsigned int* __restrict__ csr,
                                              const __half* __restrict__ tx0,
                                              __half* __restrict__ y, int N,
                                              const float* __restrict__ gstats,
                                              const float* __restrict__ tstats) {
    int lane = threadIdx.x & 63;
    int wv = (blockIdx.x * 256 + threadIdx.x) >> 6;
    int g = lane >> 3, li = lane & 7;
    int node = wv * 8 + g;
    int e = 0, e1 = 0;
    if (node < N) {
        int2 info = rowinfo[node];
        e = info.x;
        e1 = info.x + info.y;
    }
    float acc[8] = {0.f, 0.f, 0.f, 0.f, 0.f, 0.f, 0.f, 0.f};
    float sw = 0.0f;
    const __half* hb = h + li * 8;
    for (; e < e1; e += 8) {
        uint4 c0 = *(const uint4*)(csr + e);
        uint4 c1 = *(const uint4*)(csr + e + 4);
        uint4 a0, a1, a2, a3, a4, a5, a6, a7;
        GATH(a0, a1, a2, a3, a4, a5, a6, a7, c0, c1);
        FMA8(a0, a1, a2, a3, a4, a5, a6, a7, c0, c1);
    }
    if (node >= N) return;
    if (gstats != nullptr) {
        float4 m0 = *(const float4*)(gstats + li * 8);
        float4 m1 = *(const float4*)(gstats + li * 8 + 4);
        float4 r0 = *(const float4*)(gstats + 64 + li * 8);
        float4 r1 = *(const float4*)(gstats + 64 + li * 8 + 4);
        acc[0] = r0.x * (acc[0] - m0.x * sw);
        acc[1] = r0.y * (acc[1] - m0.y * sw);
        acc[2] = r0.z * (acc[2] - m0.z * sw);
        acc[3] = r0.w * (acc[3] - m0.w * sw);
        acc[4] = r1.x * (acc[4] - m1.x * sw);
        acc[5] = r1.y * (acc[5] - m1.y * sw);
        acc[6] = r1.z * (acc[6] - m1.z * sw);
        acc[7] = r1.w * (acc[7] - m1.w * sw);
    }
    if (tx0 != nullptr) {
        uint4 tq = *(const uint4*)(tx0 + (size_t)node * NCH + li * 8);
        float tv[8];
        float2 f;
        f = __half22float2(*(__half2*)&tq.x); tv[0] = f.x; tv[1] = f.y;
        f = __half22float2(*(__half2*)&tq.y); tv[2] = f.x; tv[3] = f.y;
        f = __half22float2(*(__half2*)&tq.z); tv[4] = f.x; tv[5] = f.y;
        f = __half22float2(*(__half2*)&tq.w); tv[6] = f.x; tv[7] = f.y;
        if (tstats != nullptr) {
            float4 m0 = *(const float4*)(tstats + li * 8);
            float4 m1 = *(const float4*)(tstats + li * 8 + 4);
            float4 r0 = *(const float4*)(tstats + 64 + li * 8);
            float4 r1 = *(const float4*)(tstats + 64 + li * 8 + 4);
            tv[0] = (tv[0] - m0.x) * r0.x; tv[1] = (tv[1] - m0.y) * r0.y;
            tv[2] = (tv[2] - m0.z) * r0.z; tv[3] = (tv[3] - m0.w) * r0.w;
            tv[4] = (tv[4] - m1.x) * r1.x; tv[5] = (tv[5] - m1.y) * r1.y;
            tv[6] = (tv[6] - m1.z) * r1.z; tv[7] = (tv[7] - m1.w) * r1.w;
        }
#pragma unroll
        for (int j = 0; j < 8; j++) acc[j] = 2.0f * acc[j] - tv[j];
    }
    uint4 o;
    __half2 hh;
    hh = __floats2half2_rn(acc[0], acc[1]); o.x = *(unsigned int*)&hh;
    hh = __floats2half2_rn(acc[2], acc[3]); o.y = *(unsigned int*)&hh;
    hh = __floats2half2_rn(acc[4], acc[5]); o.z = *(unsigned int*)&hh;
    hh = __floats2half2_rn(acc[6], acc[7]); o.w = *(unsigned int*)&hh;
    *(uint4*)(y + (size_t)node * NCH + li * 8) = o;
}

// ---------------- MFMA dense combine + bias + ReLU + banked instance-norm stats ----------------
template <typename TOUT>
__global__ __launch_bounds__(256) void k_dmm(const __half* __restrict__ tx0,
                                             const __half* __restrict__ tx1,
                                             const __half* __restrict__ tx2,
                                             const _Float16* __restrict__ Wb,
                                             const float* __restrict__ b,
                                             TOUT* __restrict__ out,
                                             float* __restrict__ statsP, int N,
                                             const float* __restrict__ tstats) {
    __shared__ float sred[64];
    __shared__ float sq[64];
    int t = threadIdx.x;
    int w = t >> 6;
    int lane = t & 63;
    if (t < 64) { sred[t] = 0.f; sq[t] = 0.f; }
    __syncthreads();

    int nb16 = blockIdx.x * 64 + w * 16;
    int m = lane & 15, q = lane >> 4;
    int row = nb16 + m;
    int rowC = (row < N) ? row : 0;
    const __half* base0 = tx0 + (size_t)rowC * NCH;
    const __half* base1 = tx1 + (size_t)rowC * NCH;
    const __half* base2 = tx2 + (size_t)rowC * NCH;

    f32x4 acc[4];
#pragma unroll
    for (int tile = 0; tile < 4; tile++) acc[tile] = (f32x4){0.f, 0.f, 0.f, 0.f};

#pragma unroll
    for (int kk = 0; kk < 6; kk++) {
        const __half* ap = (kk < 2 ? base0 : (kk < 4 ? base1 : base2)) + (kk & 1) * 32 + q * 8;
        f16x8 a = *(const f16x8*)ap;
        if (kk < 2 && tstats != nullptr) {
            int cbase = (kk & 1) * 32 + q * 8;
#pragma unroll
            for (int j = 0; j < 8; j++) {
                float v = (float)a[j];
                a[j] = (_Float16)((v - tstats[cbase + j]) * tstats[64 + cbase + j]);
            }
        }
#pragma unroll
        for (int tile = 0; tile < 4; tile++) {
            f16x8 bf = *(const f16x8*)(Wb + ((size_t)(tile * 6 + kk) * 64 + lane) * 8);
            acc[tile] = __builtin_amdgcn_mfma_f32_16x16x32_f16(a, bf, acc[tile], 0, 0, 0);
        }
    }

#pragma unroll
    for (int tile = 0; tile < 4; tile++) {
        int ch = tile * 16 + m;
        float bb = b[ch];
        float s = 0.f, qq = 0.f;
#pragma unroll
        for (int r = 0; r < 4; r++) {
            int node = nb16 + q * 4 + r;
            float v = fmaxf(acc[tile][r] + bb, 0.f);
            if (node < N) {
                out[(size_t)node * NCH + ch] = (TOUT)v;
                s += v;
                qq = fmaf(v, v, qq);
            }
        }
        s += __shfl_xor(s, 16, 64);  s += __shfl_xor(s, 32, 64);
        qq += __shfl_xor(qq, 16, 64); qq += __shfl_xor(qq, 32, 64);
        if (q == 0) { atomicAdd(&sred[ch], s); atomicAdd(&sq[ch], qq); }
    }
    __syncthreads();
    if (t < 64) {
        int bank = blockIdx.x & (SBANKS - 1);
        atomicAdd(&statsP[bank * 128 + t], sred[t]);
        atomicAdd(&statsP[bank * 128 + 64 + t], sq[t]);
    }
}

__global__ void k_final(float* __restrict__ statsP, float invN) {
    int c = threadIdx.x;  // 64
    float S = 0.f, Q = 0.f;
    for (int k = 0; k < SBANKS; k++) {
        S += statsP[k * 128 + c];
        Q += statsP[k * 128 + 64 + c];
    }
    float m = S * invN;
    float var = Q * invN - m * m;
    statsP[SBANKS * 128 + c] = m;
    statsP[SBANKS * 128 + 64 + c] = rsqrtf(var + EPS);
}

// normalize fp16 A -> fp32 out (vectorized: 8 halves / thread)
__global__ void k_norm_hf(const __half* __restrict__ a, float* __restrict__ o,
                          const float* __restrict__ statsP, int total8) {
    int i = blockIdx.x * blockDim.x + threadIdx.x;
    if (i >= total8) return;
    int c0 = (i & 7) * 8;   // NCH=64: element (i*8) % 64
    const float* mp = statsP + SBANKS * 128;
    float4 m0 = *(const float4*)(mp + c0);
    float4 m1 = *(const float4*)(mp + c0 + 4);
    float4 r0 = *(const float4*)(mp + 64 + c0);
    float4 r1 = *(const float4*)(mp + 64 + c0 + 4);
    uint4 q = *(const uint4*)(a + (size_t)i * 8);
    float2 f;
    float4 o0, o1;
    f = __half22float2(*(__half2*)&q.x); o0.x = (f.x - m0.x) * r0.x; o0.y = (f.y - m0.y) * r0.y;
    f = __half22float2(*(__half2*)&q.y); o0.z = (f.x - m0.z) * r0.z; o0.w = (f.y - m0.w) * r0.w;
    f = __half22float2(*(__half2*)&q.z); o1.x = (f.x - m1.x) * r1.x; o1.y = (f.y - m1.y) * r1.y;
    f = __half22float2(*(__half2*)&q.w); o1.z = (f.x - m1.z) * r1.z; o1.w = (f.y - m1.w) * r1.w;
    *(float4*)(o + (size_t)i * 8) = o0;
    *(float4*)(o + (size_t)i * 8 + 4) = o1;
}

// ---------------- launcher ----------------
extern "C" void kernel_launch(void* const* d_in, const int* in_sizes, int n_in,
                              void* d_out, int out_size, void* d_ws, size_t ws_size,
                              hipStream_t stream) {
    const float* x  = (const float*)d_in[0];
    const int*   ei = (const int*)d_in[1];
    const float* W1 = (const float*)d_in[2];
    const float* b1 = (const float*)d_in[3];
    const float* W2 = (const float*)d_in[4];
    const float* b2 = (const float*)d_in[5];
    float* out = (float*)d_out;

    const int N = in_sizes[0] / NCH;
    const int E = in_sizes[1] / 2;
    const int* src = ei;
    const int* dst = ei + E;
    const int nbuck = (N + 255) >> BSHIFT;
    const int PE = E + nbuck * PADRES + 8;     // padded csr extent

    // workspace carve (256B aligned)
    char* p = (char*)d_ws;
    auto alloc = [&](size_t bytes) {
        void* r = (void*)p;
        p += ((bytes + 255) / 256) * 256;
        return r;
    };
    float*  dinv     = (float*)alloc((size_t)131072 * 4);  // padded: k_weights may read OOB-src from slack
    int2*   rowinfo  = (int2*)alloc((size_t)N * 8);
    unsigned int* csr = (unsigned int*)alloc((size_t)PE * 4);
    __half* xh       = (__half*)alloc((size_t)N * NCH * 2);
    __half* Tx1      = (__half*)alloc((size_t)N * NCH * 2);
    __half* Tx2      = (__half*)alloc((size_t)N * NCH * 2);
    __half* A        = (__half*)alloc((size_t)N * NCH * 2);
    __half* A2       = (__half*)alloc((size_t)N * NCH * 2);
    _Float16* Wb1    = (_Float16*)alloc(12288 * 2);
    _Float16* Wb2    = (_Float16*)alloc(12288 * 2);
    int*    gbase    = (int*)alloc((size_t)(nbuck + 1) * 4);
    int*    gcur     = (int*)alloc((size_t)nbuck * 4);
    const int statsFloats = SBANKS * 128 + 128;
    // cnt and stats adjacent -> single memset
    int*    cnt      = (int*)alloc((size_t)nbuck * 4 + (size_t)2 * statsFloats * 4);
    float*  stats1   = (float*)(cnt + nbuck);
    float*  stats2   = stats1 + statsFloats;
    const float* nrm1 = stats1 + SBANKS * 128;  // m[64], r[64] after k_final

    // binned aliases Tx1 (dead before first k_prop writes Tx1)
    int2* binned = (int2*)Tx1;

    hipMemsetAsync(cnt, 0, (size_t)nbuck * 4 + (size_t)2 * statsFloats * 4, stream);

    const int TB = 256;
    int nbin = (E + BINCAP - 1) / BINCAP;
    if (nbin < NBINMIN) nbin = NBINMIN;
    const int perBin = (E + nbin - 1) / nbin;
    const int perH = (E + NHIST - 1) / NHIST;
    const int castTotal = N * NCH;
    const int castB = (castTotal / 4 + TB - 1) / TB;
    k_front<<<castB + 96 + NHIST, TB, 0, stream>>>(x, xh, castTotal, castB,
                                                   W1, Wb1, W2, Wb2,
                                                   dst, cnt, E, perH, nbuck);
    k_bscan<<<1, 512, 0, stream>>>(cnt, gbase, gcur, nbuck, E);
    k_bin<<<nbin, 512, 0, stream>>>(src, dst, gcur, binned, E, perBin, nbuck);
    k_bucket<<<nbuck, 512, 0, stream>>>(binned, gbase, dinv, rowinfo, csr, N, nbuck);
    k_weights<<<(PE + TB - 1) / TB, TB, 0, stream>>>(csr, dinv, PE);

    const int propWaves = (N + 7) / 8;
    const int propBlocks = (propWaves + 3) / 4;
    const int dmmBlocks = (N + 63) / 64;
    const int total8 = (N * NCH) / 8;
    const int normBlocks = (total8 + TB - 1) / TB;
    const float invN = 1.0f / (float)N;

    // ---- layer 1 (raw x) ----
    k_prop<<<propBlocks, TB, 0, stream>>>(xh, rowinfo, csr, nullptr, Tx1, N, nullptr, nullptr);
    k_prop<<<propBlocks, TB, 0, stream>>>(Tx1, rowinfo, csr, xh, Tx2, N, nullptr, nullptr);
    k_dmm<__half><<<dmmBlocks, TB, 0, stream>>>(xh, Tx1, Tx2, Wb1, b1, A, stats1, N, nullptr);
    k_final<<<1, 64, 0, stream>>>(stats1, invN);

    // ---- layer 2 (A normalized on the fly via nrm1) ----
    k_prop<<<propBlocks, TB, 0, stream>>>(A, rowinfo, csr, nullptr, Tx1, N, nrm1, nullptr);
    k_prop<<<propBlocks, TB, 0, stream>>>(Tx1, rowinfo, csr, A, Tx2, N, nullptr, nrm1);
    k_dmm<__half><<<dmmBlocks, TB, 0, stream>>>(A, Tx1, Tx2, Wb2, b2, A2, stats2, N, nrm1);
    k_final<<<1, 64, 0, stream>>>(stats2, invN);
    k_norm_hf<<<normBlocks, TB, 0, stream>>>(A2, out, stats2, total8);
}

// Round 6
// 324.501 us; speedup vs baseline: 1.0263x; 1.0263x over previous
//
#include <hip/hip_runtime.h>
#include <hip/hip_fp16.h>

#define NCH 64
#define EPS 1e-5f
#define SBANKS 32   // stats atomic banks
#define BSHIFT 8    // 256 dst nodes per bucket
#define NHIST 256   // blocks in hist pass
#define BINCAP 3200 // max edges per k_bin block (LDS 34KB -> 2 blocks/CU) [R4 best]
#define NBINMIN 512 // min k_bin blocks [R4 best; 1024x512thr was slower]
#define PADRES 2048 // per-bucket csr slack for 8-padding (256*7 + align < 2048)
#define RSHIFT 14   // src-range windows of 16384 rows (2MB) for L2 locality
#define SRCMASK 0x1FFFFu
#define QW_SCALE 32767.0f
#define QW_INV (1.0f/32767.0f)

typedef _Float16 f16x8 __attribute__((ext_vector_type(8)));
typedef float f32x4 __attribute__((ext_vector_type(4)));

// ---------------- fused front: x cast + W1/W2 pack + bucket histogram ----------------
__global__ __launch_bounds__(256) void k_front(const float* __restrict__ x, __half* __restrict__ xh,
                                               int castTotal, int castB,
                                               const float* __restrict__ W1, _Float16* __restrict__ Wb1,
                                               const float* __restrict__ W2, _Float16* __restrict__ Wb2,
                                               const int* __restrict__ dst, int* __restrict__ cnt,
                                               int E, int per, int nbuck) {
    int bid = blockIdx.x;
    if (bid < castB) {
        int i = (bid * 256 + threadIdx.x) * 4;
        if (i < castTotal) {
            float4 f = *(const float4*)(x + i);
            __half2* o = (__half2*)(xh + i);
            o[0] = __floats2half2_rn(f.x, f.y);
            o[1] = __floats2half2_rn(f.z, f.w);
        }
        return;
    }
    if (bid < castB + 96) {
        // W pack: Wb[((tile*6+kk)*64+lane)*8+j] = W[kk*32+(lane>>4)*8+j][tile*16+(lane&15)]
        int wb = bid - castB;
        const float* W = (wb < 48) ? W1 : W2;
        _Float16* Wb = (wb < 48) ? Wb1 : Wb2;
        int idx = (wb % 48) * 256 + threadIdx.x;   // 0..12287
        int j = idx & 7;
        int lane = (idx >> 3) & 63;
        int tk = idx >> 9;
        int tile = tk / 6, kk = tk % 6;
        int k = kk * 32 + (lane >> 4) * 8 + j;
        int n = tile * 16 + (lane & 15);
        Wb[idx] = (_Float16)W[k * 64 + n];
        return;
    }
    // histogram role
    __shared__ int lh[512];
    int hb = bid - castB - 96;
    for (int t = threadIdx.x; t < nbuck; t += 256) lh[t] = 0;
    __syncthreads();
    int lo = hb * per, hi = min(E, lo + per);
    for (int e = lo + threadIdx.x; e < hi; e += 256)
        atomicAdd(&lh[dst[e] >> BSHIFT], 1);
    __syncthreads();
    for (int t = threadIdx.x; t < nbuck; t += 256)
        if (lh[t]) atomicAdd(&cnt[t], lh[t]);
}

// ---------------- scan bucket counts -> base & cursor ----------------
__global__ void k_bscan(const int* __restrict__ cnt, int* __restrict__ gbase,
                        int* __restrict__ gcur, int nbuck, int E) {
    __shared__ int s[512];
    int t = threadIdx.x;
    int v = (t < nbuck) ? cnt[t] : 0;
    s[t] = v;
    __syncthreads();
    for (int off = 1; off < 512; off <<= 1) {
        int add = (t >= off) ? s[t - off] : 0;
        __syncthreads();
        s[t] += add;
        __syncthreads();
    }
    if (t < nbuck) { int ex = s[t] - v; gbase[t] = ex; gcur[t] = ex; }
    if (t == 0) gbase[nbuck] = E;
}

// ---------------- bin edges into bucket segments (LDS counting sort) ----------------
__global__ __launch_bounds__(256) void k_bin(const int* __restrict__ src,
                                             const int* __restrict__ dst,
                                             int* __restrict__ gcur,
                                             int2* __restrict__ binned, int E, int per, int nbuck) {
    __shared__ int lh[512];     // per-block bucket counts
    __shared__ int lsc[512];    // exclusive scan (local run starts)
    __shared__ int lbase[512];  // reserved global run bases
    __shared__ int lcur[512];   // scatter cursors
    __shared__ int2 sedge[BINCAP];
    int t = threadIdx.x;
    for (int i = t; i < 512; i += 256) lh[i] = 0;
    __syncthreads();
    int lo = blockIdx.x * per, hi = min(E, lo + per);
    for (int e = lo + t; e < hi; e += 256)
        atomicAdd(&lh[dst[e] >> BSHIFT], 1);
    __syncthreads();
    int v0 = lh[t], v1 = lh[t + 256];
    lsc[t] = v0; lsc[t + 256] = v1;
    __syncthreads();
    for (int off = 1; off < 512; off <<= 1) {
        int a0 = (t >= off) ? lsc[t - off] : 0;
        int a1 = (t + 256 >= off) ? lsc[t + 256 - off] : 0;
        __syncthreads();
        lsc[t] += a0; lsc[t + 256] += a1;
        __syncthreads();
    }
    lsc[t] -= v0; lsc[t + 256] -= v1;
    if (t < nbuck && v0) lbase[t] = atomicAdd(&gcur[t], v0);
    if (t + 256 < nbuck && v1) lbase[t + 256] = atomicAdd(&gcur[t + 256], v1);
    lcur[t] = lsc[t]; lcur[t + 256] = lsc[t + 256];
    __syncthreads();
    for (int e = lo + t; e < hi; e += 256) {
        int d = dst[e];
        int b = d >> BSHIFT;
        int pos = atomicAdd(&lcur[b], 1);
        sedge[pos] = make_int2(src[e], d);
    }
    __syncthreads();
    int cntE = hi - lo;
    for (int i = t; i < cntE; i += 256) {
        int2 sd = sedge[i];
        int b = sd.y >> BSHIFT;
        binned[lbase[b] + (i - lsc[b])] = sd;
    }
}

// ---------------- per-bucket CSR build, rows padded to x8, src-range ordered ----------------
__global__ __launch_bounds__(256) void k_bucket(const int2* __restrict__ binned,
                                                const int* __restrict__ gbase,
                                                float* __restrict__ dinv,
                                                int2* __restrict__ rowinfo,
                                                unsigned int* __restrict__ csr, int N, int nbuck) {
    __shared__ int hist8[256 * 8];   // (node, src-range) counts
    __shared__ int cur8[256 * 8];    // scatter cursors
    __shared__ int ldeg[256];
    __shared__ int ltmp[256];
    int b = blockIdx.x;
    int t = threadIdx.x;
    int nodeLo = b << BSHIFT;
    int nHere = min(256, N - nodeLo);
    int e0 = gbase[b], e1 = gbase[b + 1];
    int pb = (gbase[b] + b * PADRES + 7) & ~7;   // 8-aligned padded base
    for (int i = t; i < 256 * 8; i += 256) hist8[i] = 0;
    __syncthreads();
    for (int e = e0 + t; e < e1; e += 256) {
        int2 sd = binned[e];
        atomicAdd(&hist8[((sd.y - nodeLo) << 3) + (sd.x >> RSHIFT)], 1);
    }
    __syncthreads();
    int c[8], deg = 0;
#pragma unroll
    for (int r = 0; r < 8; r++) { c[r] = hist8[(t << 3) + r]; deg += c[r]; }
    int pdeg = (deg + 7) & ~7;
    ldeg[t] = deg;
    if (t < nHere) dinv[nodeLo + t] = (deg > 0) ? rsqrtf((float)deg) : 0.0f;
    ltmp[t] = pdeg;
    __syncthreads();
    for (int off = 1; off < 256; off <<= 1) {
        int add = (t >= off) ? ltmp[t - off] : 0;
        __syncthreads();
        ltmp[t] += add;
        __syncthreads();
    }
    int lstart = ltmp[t] - pdeg;
    if (t < nHere) rowinfo[nodeLo + t] = make_int2(pb + lstart, pdeg);
    // within-row range starts
    int run = lstart;
#pragma unroll
    for (int r = 0; r < 8; r++) { cur8[(t << 3) + r] = run; run += c[r]; }
    __syncthreads();
    for (int e = e0 + t; e < e1; e += 256) {
        int2 sd = binned[e];
        int dl = sd.y - nodeLo;
        int pos = atomicAdd(&cur8[(dl << 3) + (sd.x >> RSHIFT)], 1);
        unsigned int dd = (unsigned int)min(ldeg[dl], 32767);
        csr[pb + pos] = (unsigned int)sd.x | (dd << 17);
    }
    __syncthreads();
    if (t < nHere) {
        int d = ldeg[t];
        int pd = (d + 7) & ~7;
        if (pd > d) {
            unsigned int fill = (d > 0) ? (csr[pb + lstart] & SRCMASK) : 0u;  // qw=0 dummy
            for (int i = d; i < pd; i++) csr[pb + lstart + i] = fill;
        }
    }
}

// ---------------- finalize weights: |w| = dinv[s]*rsqrt(deg_d), 15-bit fixed-point ----------------
__global__ void k_weights(unsigned int* __restrict__ csr, const float* __restrict__ dinv, int PE) {
    int e = blockIdx.x * blockDim.x + threadIdx.x;
    if (e < PE) {
        unsigned int v = csr[e];
        unsigned int d = v >> 17;
        if (d == 0) return;                       // padding dummy: keep qw=0
        unsigned int s = v & SRCMASK;
        float aw = dinv[s] * rsqrtf((float)d);    // in [0,1]
        unsigned int qw = (unsigned int)(aw * QW_SCALE + 0.5f);
        csr[e] = s | (qw << 17);
    }
}

// ---------------- propagation: y = [2*]prop(gnorm(h)) [- tnorm(tx0)] ----------------
// Wave = 8 dst nodes; 8-lane group per node; lane owns 8 fixed channels (16B).
// Rows padded to x8 and src-range-ordered: pure unroll-8 body, no tail.
// v6: (a) csr quads for next iter prefetched (+8 VGPR only; R1's full gather
// pipeline traded ILP for TLP 1:1 and lost). (b) stats finalization folded in:
// when gbank/tbank non-null, each block reduces the SBANKS banks into LDS m/r
// (replaces the separate 1-block k_final kernel + its serialization point).

#define GATH(A0,A1,A2,A3,A4,A5,A6,A7, C0, C1) \
    A0 = *(const uint4*)(hb + (size_t)(C0.x & SRCMASK) * NCH); \
    A1 = *(const uint4*)(hb + (size_t)(C0.y & SRCMASK) * NCH); \
    A2 = *(const uint4*)(hb + (size_t)(C0.z & SRCMASK) * NCH); \
    A3 = *(const uint4*)(hb + (size_t)(C0.w & SRCMASK) * NCH); \
    A4 = *(const uint4*)(hb + (size_t)(C1.x & SRCMASK) * NCH); \
    A5 = *(const uint4*)(hb + (size_t)(C1.y & SRCMASK) * NCH); \
    A6 = *(const uint4*)(hb + (size_t)(C1.z & SRCMASK) * NCH); \
    A7 = *(const uint4*)(hb + (size_t)(C1.w & SRCMASK) * NCH);

#define FMA1(A, W) { \
    float2 f; \
    f = __half22float2(*(const __half2*)&A.x); acc[0] = fmaf(W, f.x, acc[0]); acc[1] = fmaf(W, f.y, acc[1]); \
    f = __half22float2(*(const __half2*)&A.y); acc[2] = fmaf(W, f.x, acc[2]); acc[3] = fmaf(W, f.y, acc[3]); \
    f = __half22float2(*(const __half2*)&A.z); acc[4] = fmaf(W, f.x, acc[4]); acc[5] = fmaf(W, f.y, acc[5]); \
    f = __half22float2(*(const __half2*)&A.w); acc[6] = fmaf(W, f.x, acc[6]); acc[7] = fmaf(W, f.y, acc[7]); }

#define FMA8(A0,A1,A2,A3,A4,A5,A6,A7, C0, C1) { \
    float w0 = -(float)(C0.x >> 17) * QW_INV; \
    float w1 = -(float)(C0.y >> 17) * QW_INV; \
    float w2 = -(float)(C0.z >> 17) * QW_INV; \
    float w3 = -(float)(C0.w >> 17) * QW_INV; \
    float w4 = -(float)(C1.x >> 17) * QW_INV; \
    float w5 = -(float)(C1.y >> 17) * QW_INV; \
    float w6 = -(float)(C1.z >> 17) * QW_INV; \
    float w7 = -(float)(C1.w >> 17) * QW_INV; \
    sw += ((w0 + w1) + (w2 + w3)) + ((w4 + w5) + (w6 + w7)); \
    FMA1(A0, w0) FMA1(A1, w1) FMA1(A2, w2) FMA1(A3, w3) \
    FMA1(A4, w4) FMA1(A5, w5) FMA1(A6, w6) FMA1(A7, w7) }

__global__ __launch_bounds__(256) void k_prop(const __half* __restrict__ h,
                                              const int2* __restrict__ rowinfo,
                                              const unsigned int* __restrict__ csr,
                                              const __half* __restrict__ tx0,
                                              __half* __restrict__ y, int N,
                                              const float* __restrict__ gbank,
                                              const float* __restrict__ tbank,
                                              float invN) {
    __shared__ float sm[64], sr[64];
    const float* bank = (gbank != nullptr) ? gbank : tbank;
    if (bank != nullptr) {
        int tt = threadIdx.x;
        if (tt < 64) {
            float S = 0.f, Q = 0.f;
            for (int k = 0; k < SBANKS; k++) {
                S += bank[k * 128 + tt];
                Q += bank[k * 128 + 64 + tt];
            }
            float m = S * invN;
            float var = Q * invN - m * m;
            sm[tt] = m;
            sr[tt] = rsqrtf(var + EPS);
        }
        __syncthreads();
    }
    int lane = threadIdx.x & 63;
    int wv = (blockIdx.x * 256 + threadIdx.x) >> 6;
    int g = lane >> 3, li = lane & 7;
    int node = wv * 8 + g;
    int e = 0, e1 = 0;
    if (node < N) {
        int2 info = rowinfo[node];
        e = info.x;
        e1 = info.x + info.y;
    }
    float acc[8] = {0.f, 0.f, 0.f, 0.f, 0.f, 0.f, 0.f, 0.f};
    float sw = 0.0f;
    const __half* hb = h + li * 8;
    uint4 c0, c1;
    if (e < e1) {
        c0 = *(const uint4*)(csr + e);
        c1 = *(const uint4*)(csr + e + 4);
    }
    for (; e < e1; e += 8) {
        int en = (e + 8 < e1) ? (e + 8) : e;
        uint4 n0 = *(const uint4*)(csr + en);
        uint4 n1 = *(const uint4*)(csr + en + 4);
        uint4 a0, a1, a2, a3, a4, a5, a6, a7;
        GATH(a0, a1, a2, a3, a4, a5, a6, a7, c0, c1);
        FMA8(a0, a1, a2, a3, a4, a5, a6, a7, c0, c1);
        c0 = n0; c1 = n1;
    }
    if (node >= N) return;
    if (gbank != nullptr) {
        float4 m0 = *(const float4*)(sm + li * 8);
        float4 m1 = *(const float4*)(sm + li * 8 + 4);
        float4 r0 = *(const float4*)(sr + li * 8);
        float4 r1 = *(const float4*)(sr + li * 8 + 4);
        acc[0] = r0.x * (acc[0] - m0.x * sw);
        acc[1] = r0.y * (acc[1] - m0.y * sw);
        acc[2] = r0.z * (acc[2] - m0.z * sw);
        acc[3] = r0.w * (acc[3] - m0.w * sw);
        acc[4] = r1.x * (acc[4] - m1.x * sw);
        acc[5] = r1.y * (acc[5] - m1.y * sw);
        acc[6] = r1.z * (acc[6] - m1.z * sw);
        acc[7] = r1.w * (acc[7] - m1.w * sw);
    }
    if (tx0 != nullptr) {
        uint4 tq = *(const uint4*)(tx0 + (size_t)node * NCH + li * 8);
        float tv[8];
        float2 f;
        f = __half22float2(*(__half2*)&tq.x); tv[0] = f.x; tv[1] = f.y;
        f = __half22float2(*(__half2*)&tq.y); tv[2] = f.x; tv[3] = f.y;
        f = __half22float2(*(__half2*)&tq.z); tv[4] = f.x; tv[5] = f.y;
        f = __half22float2(*(__half2*)&tq.w); tv[6] = f.x; tv[7] = f.y;
        if (tbank != nullptr) {
            float4 m0 = *(const float4*)(sm + li * 8);
            float4 m1 = *(const float4*)(sm + li * 8 + 4);
            float4 r0 = *(const float4*)(sr + li * 8);
            float4 r1 = *(const float4*)(sr + li * 8 + 4);
            tv[0] = (tv[0] - m0.x) * r0.x; tv[1] = (tv[1] - m0.y) * r0.y;
            tv[2] = (tv[2] - m0.z) * r0.z; tv[3] = (tv[3] - m0.w) * r0.w;
            tv[4] = (tv[4] - m1.x) * r1.x; tv[5] = (tv[5] - m1.y) * r1.y;
            tv[6] = (tv[6] - m1.z) * r1.z; tv[7] = (tv[7] - m1.w) * r1.w;
        }
#pragma unroll
        for (int j = 0; j < 8; j++) acc[j] = 2.0f * acc[j] - tv[j];
    }
    uint4 o;
    __half2 hh;
    hh = __floats2half2_rn(acc[0], acc[1]); o.x = *(unsigned int*)&hh;
    hh = __floats2half2_rn(acc[2], acc[3]); o.y = *(unsigned int*)&hh;
    hh = __floats2half2_rn(acc[4], acc[5]); o.z = *(unsigned int*)&hh;
    hh = __floats2half2_rn(acc[6], acc[7]); o.w = *(unsigned int*)&hh;
    *(uint4*)(y + (size_t)node * NCH + li * 8) = o;
}

// ---------------- MFMA dense combine + bias + ReLU + banked instance-norm stats ----------------
// tbank non-null: finalize prev-layer stats from banks into LDS (replaces k_final).
template <typename TOUT>
__global__ __launch_bounds__(256) void k_dmm(const __half* __restrict__ tx0,
                                             const __half* __restrict__ tx1,
                                             const __half* __restrict__ tx2,
                                             const _Float16* __restrict__ Wb,
                                             const float* __restrict__ b,
                                             TOUT* __restrict__ out,
                                             float* __restrict__ statsP, int N,
                                             const float* __restrict__ tbank,
                                             float invN) {
    __shared__ float sred[64];
    __shared__ float sq[64];
    __shared__ float tm[64];
    __shared__ float tr[64];
    int t = threadIdx.x;
    int w = t >> 6;
    int lane = t & 63;
    if (t < 64) {
        sred[t] = 0.f; sq[t] = 0.f;
        if (tbank != nullptr) {
            float S = 0.f, Q = 0.f;
            for (int k = 0; k < SBANKS; k++) {
                S += tbank[k * 128 + t];
                Q += tbank[k * 128 + 64 + t];
            }
            float m = S * invN;
            float var = Q * invN - m * m;
            tm[t] = m;
            tr[t] = rsqrtf(var + EPS);
        }
    }
    __syncthreads();

    int nb16 = blockIdx.x * 64 + w * 16;
    int m = lane & 15, q = lane >> 4;
    int row = nb16 + m;
    int rowC = (row < N) ? row : 0;
    const __half* base0 = tx0 + (size_t)rowC * NCH;
    const __half* base1 = tx1 + (size_t)rowC * NCH;
    const __half* base2 = tx2 + (size_t)rowC * NCH;

    f32x4 acc[4];
#pragma unroll
    for (int tile = 0; tile < 4; tile++) acc[tile] = (f32x4){0.f, 0.f, 0.f, 0.f};

#pragma unroll
    for (int kk = 0; kk < 6; kk++) {
        const __half* ap = (kk < 2 ? base0 : (kk < 4 ? base1 : base2)) + (kk & 1) * 32 + q * 8;
        f16x8 a = *(const f16x8*)ap;
        if (kk < 2 && tbank != nullptr) {
            int cbase = (kk & 1) * 32 + q * 8;
#pragma unroll
            for (int j = 0; j < 8; j++) {
                float v = (float)a[j];
                a[j] = (_Float16)((v - tm[cbase + j]) * tr[cbase + j]);
            }
        }
#pragma unroll
        for (int tile = 0; tile < 4; tile++) {
            f16x8 bf = *(const f16x8*)(Wb + ((size_t)(tile * 6 + kk) * 64 + lane) * 8);
            acc[tile] = __builtin_amdgcn_mfma_f32_16x16x32_f16(a, bf, acc[tile], 0, 0, 0);
        }
    }

#pragma unroll
    for (int tile = 0; tile < 4; tile++) {
        int ch = tile * 16 + m;
        float bb = b[ch];
        float s = 0.f, qq = 0.f;
#pragma unroll
        for (int r = 0; r < 4; r++) {
            int node = nb16 + q * 4 + r;
            float v = fmaxf(acc[tile][r] + bb, 0.f);
            if (node < N) {
                out[(size_t)node * NCH + ch] = (TOUT)v;
                s += v;
                qq = fmaf(v, v, qq);
            }
        }
        s += __shfl_xor(s, 16, 64);  s += __shfl_xor(s, 32, 64);
        qq += __shfl_xor(qq, 16, 64); qq += __shfl_xor(qq, 32, 64);
        if (q == 0) { atomicAdd(&sred[ch], s); atomicAdd(&sq[ch], qq); }
    }
    __syncthreads();
    if (t < 64) {
        int bank = blockIdx.x & (SBANKS - 1);
        atomicAdd(&statsP[bank * 128 + t], sred[t]);
        atomicAdd(&statsP[bank * 128 + 64 + t], sq[t]);
    }
}

// normalize fp16 A -> fp32 out (vectorized: 8 halves / thread; finalizes stats
// from banks per-block — replaces k_final for layer 2)
__global__ __launch_bounds__(256) void k_norm_hf(const __half* __restrict__ a, float* __restrict__ o,
                                                 const float* __restrict__ sbank, float invN,
                                                 int total8) {
    __shared__ float sm[64];
    __shared__ float sr[64];
    int t = threadIdx.x;
    if (t < 64) {
        float S = 0.f, Q = 0.f;
        for (int k = 0; k < SBANKS; k++) {
            S += sbank[k * 128 + t];
            Q += sbank[k * 128 + 64 + t];
        }
        float m = S * invN;
        float var = Q * invN - m * m;
        sm[t] = m;
        sr[t] = rsqrtf(var + EPS);
    }
    __syncthreads();
    int i = blockIdx.x * 256 + t;
    if (i >= total8) return;
    int c0 = (i & 7) * 8;   // NCH=64: element (i*8) % 64
    float4 m0 = *(const float4*)(sm + c0);
    float4 m1 = *(const float4*)(sm + c0 + 4);
    float4 r0 = *(const float4*)(sr + c0);
    float4 r1 = *(const float4*)(sr + c0 + 4);
    uint4 q = *(const uint4*)(a + (size_t)i * 8);
    float2 f;
    float4 o0, o1;
    f = __half22float2(*(__half2*)&q.x); o0.x = (f.x - m0.x) * r0.x; o0.y = (f.y - m0.y) * r0.y;
    f = __half22float2(*(__half2*)&q.y); o0.z = (f.x - m0.z) * r0.z; o0.w = (f.y - m0.w) * r0.w;
    f = __half22float2(*(__half2*)&q.z); o1.x = (f.x - m1.x) * r1.x; o1.y = (f.y - m1.y) * r1.y;
    f = __half22float2(*(__half2*)&q.w); o1.z = (f.x - m1.z) * r1.z; o1.w = (f.y - m1.w) * r1.w;
    *(float4*)(o + (size_t)i * 8) = o0;
    *(float4*)(o + (size_t)i * 8 + 4) = o1;
}

// ---------------- launcher ----------------
extern "C" void kernel_launch(void* const* d_in, const int* in_sizes, int n_in,
                              void* d_out, int out_size, void* d_ws, size_t ws_size,
                              hipStream_t stream) {
    const float* x  = (const float*)d_in[0];
    const int*   ei = (const int*)d_in[1];
    const float* W1 = (const float*)d_in[2];
    const float* b1 = (const float*)d_in[3];
    const float* W2 = (const float*)d_in[4];
    const float* b2 = (const float*)d_in[5];
    float* out = (float*)d_out;

    const int N = in_sizes[0] / NCH;
    const int E = in_sizes[1] / 2;
    const int* src = ei;
    const int* dst = ei + E;
    const int nbuck = (N + 255) >> BSHIFT;
    const int PE = E + nbuck * PADRES + 8;     // padded csr extent

    // workspace carve (256B aligned)
    char* p = (char*)d_ws;
    auto alloc = [&](size_t bytes) {
        void* r = (void*)p;
        p += ((bytes + 255) / 256) * 256;
        return r;
    };
    float*  dinv     = (float*)alloc((size_t)131072 * 4);  // padded: k_weights may read OOB-src from slack
    int2*   rowinfo  = (int2*)alloc((size_t)N * 8);
    unsigned int* csr = (unsigned int*)alloc((size_t)PE * 4);
    __half* xh       = (__half*)alloc((size_t)N * NCH * 2);
    __half* Tx1      = (__half*)alloc((size_t)N * NCH * 2);
    __half* Tx2      = (__half*)alloc((size_t)N * NCH * 2);
    __half* A        = (__half*)alloc((size_t)N * NCH * 2);
    __half* A2       = (__half*)alloc((size_t)N * NCH * 2);
    _Float16* Wb1    = (_Float16*)alloc(12288 * 2);
    _Float16* Wb2    = (_Float16*)alloc(12288 * 2);
    int*    gbase    = (int*)alloc((size_t)(nbuck + 1) * 4);
    int*    gcur     = (int*)alloc((size_t)nbuck * 4);
    const int statsFloats = SBANKS * 128 + 128;
    // cnt and stats adjacent -> single memset
    int*    cnt      = (int*)alloc((size_t)nbuck * 4 + (size_t)2 * statsFloats * 4);
    float*  stats1   = (float*)(cnt + nbuck);
    float*  stats2   = stats1 + statsFloats;

    // binned aliases Tx1 (dead before first k_prop writes Tx1)
    int2* binned = (int2*)Tx1;

    hipMemsetAsync(cnt, 0, (size_t)nbuck * 4 + (size_t)2 * statsFloats * 4, stream);

    const int TB = 256;
    int nbin = (E + BINCAP - 1) / BINCAP;
    if (nbin < NBINMIN) nbin = NBINMIN;
    const int perBin = (E + nbin - 1) / nbin;
    const int perH = (E + NHIST - 1) / NHIST;
    const int castTotal = N * NCH;
    const int castB = (castTotal / 4 + TB - 1) / TB;
    k_front<<<castB + 96 + NHIST, TB, 0, stream>>>(x, xh, castTotal, castB,
                                                   W1, Wb1, W2, Wb2,
                                                   dst, cnt, E, perH, nbuck);
    k_bscan<<<1, 512, 0, stream>>>(cnt, gbase, gcur, nbuck, E);
    k_bin<<<nbin, TB, 0, stream>>>(src, dst, gcur, binned, E, perBin, nbuck);
    k_bucket<<<nbuck, TB, 0, stream>>>(binned, gbase, dinv, rowinfo, csr, N, nbuck);
    k_weights<<<(PE + TB - 1) / TB, TB, 0, stream>>>(csr, dinv, PE);

    const int propWaves = (N + 7) / 8;
    const int propBlocks = (propWaves + 3) / 4;
    const int dmmBlocks = (N + 63) / 64;
    const int total8 = (N * NCH) / 8;
    const int normBlocks = (total8 + TB - 1) / TB;
    const float invN = 1.0f / (float)N;

    // ---- layer 1 (raw x) ----
    k_prop<<<propBlocks, TB, 0, stream>>>(xh, rowinfo, csr, nullptr, Tx1, N, nullptr, nullptr, invN);
    k_prop<<<propBlocks, TB, 0, stream>>>(Tx1, rowinfo, csr, xh, Tx2, N, nullptr, nullptr, invN);
    k_dmm<__half><<<dmmBlocks, TB, 0, stream>>>(xh, Tx1, Tx2, Wb1, b1, A, stats1, N, nullptr, invN);

    // ---- layer 2 (A normalized on the fly from stats1 banks) ----
    k_prop<<<propBlocks, TB, 0, stream>>>(A, rowinfo, csr, nullptr, Tx1, N, stats1, nullptr, invN);
    k_prop<<<propBlocks, TB, 0, stream>>>(Tx1, rowinfo, csr, A, Tx2, N, nullptr, stats1, invN);
    k_dmm<__half><<<dmmBlocks, TB, 0, stream>>>(A, Tx1, Tx2, Wb2, b2, A2, stats2, N, stats1, invN);
    k_norm_hf<<<normBlocks, TB, 0, stream>>>(A2, out, stats2, invN, total8);
}